// Round 4
// baseline (362.747 us; speedup 1.0000x reference)
//
#include <hip/hip_runtime.h>
#include <math.h>

// SelfAttention fused pipeline, MI355X gfx950.
// B=4 S=2048 D=1024 H=8 DK=128.
// R4: flash v3 — LDS was saturated (R3 analysis: 99 B/cyc vs 85 ceiling).
// Split traffic: K frags via LDS DMA (ping-pong, 1 barrier/tile), V frags
// direct from global (served by L1: one 512-thread block per CU so all 8
// waves share one V tile in L1). Packs fused into one dispatch.

typedef __bf16 bf16;
typedef __bf16 bf16x2 __attribute__((ext_vector_type(2)));
typedef __bf16 bf16x4 __attribute__((ext_vector_type(4)));
typedef __bf16 bf16x8 __attribute__((ext_vector_type(8)));
typedef float  f32x4  __attribute__((ext_vector_type(4)));
typedef float  f32x16 __attribute__((ext_vector_type(16)));
typedef int    i32x4  __attribute__((ext_vector_type(4)));

constexpr float QK_SCALE = 0.08838834764831845f;  // 1/sqrt(128)

__device__ __forceinline__ void load16_to_lds(const bf16* g, bf16* l) {
    __builtin_amdgcn_global_load_lds((const __attribute__((address_space(1))) void*)g,
                                     (__attribute__((address_space(3))) void*)l,
                                     16, 0, 0);
}

__device__ __forceinline__ int packbf2(float a, float b) {
    bf16x2 v; v[0] = (bf16)a; v[1] = (bf16)b;
    return __builtin_bit_cast(int, v);
}

// ---------------------------------------------------------------------------
// NT GEMM (validated R1-R3): C[m,n] = sum_k A[m,k]*B[n,k]. 128x128, BK=32.
// CMODE 1: QKV epilogue (Q,K->qk; V->vT transposed, MASKED; bias).
// CMODE 2: f32 C + bias (output projection).
// ---------------------------------------------------------------------------
template <int CMODE>
__global__ __launch_bounds__(256, 2)
void gemm_nt(const bf16* __restrict__ A, const bf16* __restrict__ Bm,
             void* __restrict__ Cv, bf16* __restrict__ vT,
             const float* __restrict__ bias, const int* __restrict__ gmask,
             int K, int lda, int ldb, int ldc)
{
    __shared__ alignas(16) bf16 As[128 * 32];
    __shared__ alignas(16) bf16 Bs[128 * 32];

    const int m0 = blockIdx.x * 128;
    const int n0 = blockIdx.y * 128;
    const int t    = threadIdx.x;
    const int lane = t & 63;
    const int wv   = t >> 6;
    const int mw   = (wv >> 1) * 64;
    const int nw   = (wv & 1) * 64;

    const int r1 = t >> 2;
    const int c1 = ((t & 3) - (r1 >> 1)) & 3;
    const int r2 = r1 + 64;
    const int c2 = ((t & 3) - (r2 >> 1)) & 3;

    const bf16* ga1 = A  + (long)(m0 + r1) * lda + c1 * 8;
    const bf16* ga2 = A  + (long)(m0 + r2) * lda + c2 * 8;
    const bf16* gb1 = Bm + (long)(n0 + r1) * ldb + c1 * 8;
    const bf16* gb2 = Bm + (long)(n0 + r2) * ldb + c2 * 8;
    bf16* la1 = &As[t * 8];
    bf16* la2 = &As[(256 + t) * 8];
    bf16* lb1 = &Bs[t * 8];
    bf16* lb2 = &Bs[(256 + t) * 8];

    const int fr = lane & 15;
    const int fq = lane >> 4;
    int aoff[4], boff[4];
#pragma unroll
    for (int i = 0; i < 4; ++i) {
        int Ra = mw + i * 16 + fr;
        aoff[i] = (Ra * 4 + ((fq + (Ra >> 1)) & 3)) * 8;
        int Rb = nw + i * 16 + fr;
        boff[i] = (Rb * 4 + ((fq + (Rb >> 1)) & 3)) * 8;
    }

    const f32x4 zero4 = {0.f, 0.f, 0.f, 0.f};
    f32x4 acc[4][4];
#pragma unroll
    for (int i = 0; i < 4; ++i)
#pragma unroll
        for (int j = 0; j < 4; ++j) acc[i][j] = zero4;

    for (int k0 = 0; k0 < K; k0 += 32) {
        __syncthreads();
        load16_to_lds(ga1, la1);
        load16_to_lds(ga2, la2);
        load16_to_lds(gb1, lb1);
        load16_to_lds(gb2, lb2);
        ga1 += 32; ga2 += 32; gb1 += 32; gb2 += 32;
        __syncthreads();
        bf16x8 af[4], bfr[4];
#pragma unroll
        for (int i = 0; i < 4; ++i) af[i]  = *(const bf16x8*)&As[aoff[i]];
#pragma unroll
        for (int j = 0; j < 4; ++j) bfr[j] = *(const bf16x8*)&Bs[boff[j]];
#pragma unroll
        for (int i = 0; i < 4; ++i)
#pragma unroll
            for (int j = 0; j < 4; ++j)
                acc[i][j] = __builtin_amdgcn_mfma_f32_16x16x32_bf16(af[i], bfr[j], acc[i][j], 0, 0, 0);
    }

    float bval = 0.f;
    if (CMODE == 1 || CMODE == 2) bval = bias[0];

#pragma unroll
    for (int i = 0; i < 4; ++i) {
        const int row0 = m0 + mw + i * 16 + fq * 4;
#pragma unroll
        for (int j = 0; j < 4; ++j) {
            const int col = n0 + nw + j * 16 + fr;
            if (CMODE == 2) {
                float* C = (float*)Cv;
#pragma unroll
                for (int r = 0; r < 4; ++r)
                    C[(long)(row0 + r) * ldc + col] = acc[i][j][r] + bval;
            } else {  // CMODE 1: QKV
                bf16* C = (bf16*)Cv;
                if (col < 2048) {
                    const float badd = (col < 1024) ? bval * QK_SCALE : bval;
#pragma unroll
                    for (int r = 0; r < 4; ++r)
                        C[(long)(row0 + r) * ldc + col] = (bf16)(acc[i][j][r] + badd);
                } else {  // V -> vT[(b*8+h)*128+dk][s], masked rows zeroed
                    const int vcol = col - 2048;
                    const int h  = vcol >> 7;
                    const int dk = vcol & 127;
                    const int b  = row0 >> 11;
                    const int s  = row0 & 2047;
                    i32x4 m4 = *(const i32x4*)(gmask + b * 2048 + s);
                    bf16x4 pack;
#pragma unroll
                    for (int r = 0; r < 4; ++r)
                        pack[r] = (bf16)((acc[i][j][r] + bval) * (float)m4[r]);
                    *(bf16x4*)&vT[((long)((b * 8 + h) * 128 + dk)) * 2048 + s] = pack;
                }
            }
        }
    }
}

// ---------------------------------------------------------------------------
// Flash v3. Block = 512 threads (8 waves) = 256 Q-rows x one (b,h); grid
// (8,32) = 256 blocks = 1/CU. Wave = 32 Q-rows. 16 key-tiles of 128.
// K staged in LDS (ping-pong 2x32KB, one barrier/tile, DMA covers full tile);
// V + mask frags read direct from global (L1-resident: 32KB tile, 8 waves).
// S^T via 32x32x16 MFMA (A=K, B=Q regs); exp-only softmax; in-reg P build;
// l via mask-MFMA; O += P.V.
// ---------------------------------------------------------------------------
__global__ __launch_bounds__(512, 2)
void flash3(const bf16* __restrict__ qk, const bf16* __restrict__ vT,
            const bf16* __restrict__ mbf, bf16* __restrict__ mh)
{
    __shared__ alignas(16) bf16 KbufA[128 * 128];   // 32 KB
    __shared__ alignas(16) bf16 KbufB[128 * 128];   // 32 KB

    const int qt = blockIdx.x, bh = blockIdx.y;
    const int b = bh >> 3, h = bh & 7;
    const int q0 = qt * 256;
    const int t = threadIdx.x, lane = t & 63, wv = t >> 6;   // wv 0..7
    const int l31 = lane & 31;
    const int hl  = lane >> 5;

    const bf16* Qb = qk + ((long)(b * 2048 + q0)) * 2048 + h * 128;
    const bf16* Kb = qk + (long)b * 2048 * 2048 + 1024 + h * 128;
    const bf16* Vb = vT + (long)bh * 128 * 2048;
    const bf16* mrow = mbf + b * 2048;

    // staging map: round rnd, thread t -> row rnd*32 + (t>>4), pos t&15,
    // logical chunk c = (pos - row)&15 (rnd*32 = 0 mod 16 -> co constant)
    const int r0 = t >> 4;
    const int co = (((t & 15) - r0) & 15) * 8;
    bf16* ldA = &KbufA[t * 8];
    bf16* ldB = &KbufB[t * 8];

    // ---- stage Q (256 rows: A=0..127, B=128..255), read Q B-frags ----
#pragma unroll
    for (int rnd = 0; rnd < 4; ++rnd)
        load16_to_lds(Qb + (long)(rnd * 32 + r0) * 2048 + co, ldA + rnd * 4096);
#pragma unroll
    for (int rnd = 0; rnd < 4; ++rnd)
        load16_to_lds(Qb + (long)((rnd + 4) * 32 + r0) * 2048 + co, ldB + rnd * 4096);
    __syncthreads();
    bf16x8 qf[8];
    {
        const bf16* qsrc = (wv < 4) ? KbufA : KbufB;
        const int rloc = (wv & 3) * 32 + l31;
#pragma unroll
        for (int kc = 0; kc < 8; ++kc) {
            int pos = ((kc * 2 + hl) + rloc) & 15;
            qf[kc] = *(const bf16x8*)&qsrc[rloc * 128 + pos * 8];
        }
    }
    __syncthreads();   // Q reads done; buffers free for K

    // prologue: K(0) -> KbufA
#pragma unroll
    for (int rnd = 0; rnd < 4; ++rnd)
        load16_to_lds(Kb + (long)(rnd * 32 + r0) * 2048 + co, ldA + rnd * 4096);

    f32x16 O4[4], lac;
#pragma unroll
    for (int r = 0; r < 16; ++r) {
        lac[r] = 0.f;
#pragma unroll
        for (int nt = 0; nt < 4; ++nt) O4[nt][r] = 0.f;
    }

    for (int tt = 0; tt < 16; ++tt) {
        const int t0 = tt * 128;
        __syncthreads();   // drains K(tt) DMA; fences prev tile's K reads

        // prefetch K(tt+1) into the other buffer (lands during this tile)
        if (tt < 15) {
            bf16* ld = (tt & 1) ? ldA : ldB;
            const bf16* src = Kb + (long)(t0 + 128 + r0) * 2048 + co;
#pragma unroll
            for (int rnd = 0; rnd < 4; ++rnd)
                load16_to_lds(src + (long)rnd * 32 * 2048, ld + rnd * 4096);
        }
        const bf16* KH = (tt & 1) ? KbufB : KbufA;

        // ---- S^T = K.Q^T per key-block; exp; in-register P-frag build ----
        bf16x8 pf[8];
#pragma unroll
        for (int mt = 0; mt < 4; ++mt) {
            f32x16 S;
#pragma unroll
            for (int r = 0; r < 16; ++r) S[r] = 0.f;
#pragma unroll
            for (int kc = 0; kc < 8; ++kc) {
                int row = mt * 32 + l31;
                int pos = ((kc * 2 + hl) + row) & 15;
                bf16x8 kf = *(const bf16x8*)&KH[row * 128 + pos * 8];
                S = __builtin_amdgcn_mfma_f32_32x32x16_bf16(kf, qf[kc], S, 0, 0, 0);
            }
            int ownd[4][2];
#pragma unroll
            for (int g = 0; g < 4; ++g) {
                float e0 = __expf(S[g * 4 + 0]);
                float e1 = __expf(S[g * 4 + 1]);
                float e2 = __expf(S[g * 4 + 2]);
                float e3 = __expf(S[g * 4 + 3]);
                ownd[g][0] = packbf2(e0, e1);
                ownd[g][1] = packbf2(e2, e3);
            }
            int rcv[4][2];
#pragma unroll
            for (int g = 0; g < 4; ++g) {
                rcv[g][0] = __shfl_xor(ownd[g][0], 32);
                rcv[g][1] = __shfl_xor(ownd[g][1], 32);
            }
#pragma unroll
            for (int kk = 0; kk < 2; ++kk) {
                i32x4 w;
                w[0] = hl ? rcv[2 * kk + 1][0] : ownd[2 * kk][0];
                w[1] = hl ? rcv[2 * kk + 1][1] : ownd[2 * kk][1];
                w[2] = hl ? ownd[2 * kk + 1][0] : rcv[2 * kk][0];
                w[3] = hl ? ownd[2 * kk + 1][1] : rcv[2 * kk][1];
                pf[mt * 2 + kk] = __builtin_bit_cast(bf16x8, w);
            }
        }

        // l += P . mask  (direct global mask frags, L1/L2-hot)
#pragma unroll
        for (int kc = 0; kc < 8; ++kc) {
            bf16x8 mf = *(const bf16x8*)(mrow + t0 + kc * 16 + hl * 8);
            lac = __builtin_amdgcn_mfma_f32_32x32x16_bf16(pf[kc], mf, lac, 0, 0, 0);
        }

        // O += P . V  (V B-frags direct from global; L1 serves wave redundancy)
#pragma unroll
        for (int kc = 0; kc < 8; ++kc) {
#pragma unroll
            for (int nt = 0; nt < 4; ++nt) {
                bf16x8 vf = *(const bf16x8*)(Vb + (long)(nt * 32 + l31) * 2048
                                             + t0 + kc * 16 + hl * 8);
                O4[nt] = __builtin_amdgcn_mfma_f32_32x32x16_bf16(pf[kc], vf, O4[nt], 0, 0, 0);
            }
        }
    }

    // ---- epilogue: O /= l, store with head reversal ----
    float invl[16];
#pragma unroll
    for (int r = 0; r < 16; ++r) invl[r] = 1.0f / lac[r];
    bf16* outb = mh + ((long)(b * 2048 + q0 + wv * 32)) * 1024 + (7 - h) * 128;
#pragma unroll
    for (int nt = 0; nt < 4; ++nt)
#pragma unroll
        for (int r = 0; r < 16; ++r) {
            int row = (r & 3) + 8 * (r >> 2) + 4 * hl;
            outb[(long)row * 1024 + nt * 32 + l31] = (bf16)(O4[nt][r] * invl[r]);
        }
}

// ---------------------------------------------------------------------------
// Fused flat packs: x->bf16, Wo->bf16, mask->bf16. One dispatch.
__global__ __launch_bounds__(256)
void pack_all(const float* __restrict__ x, const float* __restrict__ Wo,
              const int* __restrict__ mask,
              bf16* __restrict__ xb, bf16* __restrict__ wob, bf16* __restrict__ mbf)
{
    const long n1 = 8192L * 1024, n2 = 1024L * 1024;
    long i = ((long)blockIdx.x * 256 + threadIdx.x) * 4;
    if (i < n1) {
        float4 f = *(const float4*)(x + i);
        bf16x4 o;
        o[0] = (bf16)f.x; o[1] = (bf16)f.y; o[2] = (bf16)f.z; o[3] = (bf16)f.w;
        *(bf16x4*)(xb + i) = o;
    } else if (i < n1 + n2) {
        long j = i - n1;
        float4 f = *(const float4*)(Wo + j);
        bf16x4 o;
        o[0] = (bf16)f.x; o[1] = (bf16)f.y; o[2] = (bf16)f.z; o[3] = (bf16)f.w;
        *(bf16x4*)(wob + j) = o;
    } else {
        long j = i - n1 - n2;
        if (j < 8192) {
            i32x4 m = *(const i32x4*)(mask + j);
            bf16x4 o;
#pragma unroll
            for (int r = 0; r < 4; ++r) o[r] = (bf16)(float)m[r];
            *(bf16x4*)(mbf + j) = o;
        }
    }
}

__global__ __launch_bounds__(256)
void pack_wt(const float* __restrict__ Wq, const float* __restrict__ Wk,
             const float* __restrict__ Wv, bf16* __restrict__ wt)
{
    __shared__ float tile[64][65];
    const int which = blockIdx.z;
    const float* W = (which == 0) ? Wq : (which == 1) ? Wk : Wv;
    const float scale = (which == 0) ? QK_SCALE : 1.0f;
    const int h  = blockIdx.y;
    const int d0 = (blockIdx.x >> 1) * 64;
    const int k0 = (blockIdx.x & 1) * 64;
    const float* Wh = W + (long)h * 1024 * 128;
#pragma unroll
    for (int it = 0; it < 16; ++it) {
        int e = it * 256 + threadIdx.x;
        int r = e >> 6, c = e & 63;
        tile[r][c] = Wh[(long)(d0 + r) * 128 + (k0 + c)];
    }
    __syncthreads();
#pragma unroll
    for (int it = 0; it < 16; ++it) {
        int e = it * 256 + threadIdx.x;
        int rk = e >> 6, cd = e & 63;
        int n = which * 1024 + h * 128 + k0 + rk;
        wt[(long)n * 1024 + d0 + cd] = (bf16)(tile[cd][rk] * scale);
    }
}

// ---------------------------------------------------------------------------
extern "C" void kernel_launch(void* const* d_in, const int* in_sizes, int n_in,
                              void* d_out, int out_size, void* d_ws, size_t ws_size,
                              hipStream_t stream)
{
    const float* x    = (const float*)d_in[0];
    const int*   mask = (const int*)d_in[1];
    const float* Wq   = (const float*)d_in[2];
    const float* Wk   = (const float*)d_in[3];
    const float* Wv   = (const float*)d_in[4];
    const float* Wo   = (const float*)d_in[5];
    const float* bias = (const float*)d_in[6];
    float* out = (float*)d_out;

    char* w = (char*)d_ws;
    bf16* xb  = (bf16*)w; w += (size_t)8192 * 1024 * 2;        // 16 MB
    bf16* wt  = (bf16*)w; w += (size_t)3072 * 1024 * 2;        //  6 MB
    bf16* wob = (bf16*)w; w += (size_t)1024 * 1024 * 2;        //  2 MB
    bf16* qk  = (bf16*)w; w += (size_t)8192 * 2048 * 2;        // 32 MB
    bf16* vT  = (bf16*)w; w += (size_t)32 * 128 * 2048 * 2;    // 16 MB
    bf16* mh  = (bf16*)w; w += (size_t)8192 * 1024 * 2;        // 16 MB
    bf16* mbf = (bf16*)w; w += (size_t)4 * 2048 * 2;           // 16 KB

    pack_all<<<9224, 256, 0, stream>>>(x, Wo, mask, xb, wob, mbf);
    pack_wt<<<dim3(32, 8, 3), 256, 0, stream>>>(Wq, Wk, Wv, wt);

    // QKV projection: M=8192 N=3072 K=1024 (V masked in epilogue)
    gemm_nt<1><<<dim3(64, 24), 256, 0, stream>>>(
        xb, wt, qk, vT, bias, mask, 1024, 1024, 1024, 2048);

    // fused attention (1 block/CU)
    flash3<<<dim3(8, 32), 512, 0, stream>>>(qk, vT, mbf, mh);

    // out = mh @ Wo^T + b: M=8192 N=1024 K=1024, fp32 out
    gemm_nt<2><<<dim3(64, 8), 256, 0, stream>>>(
        mh, wob, out, nullptr, bias, nullptr, 1024, 1024, 1024, 1024);
}

// Round 5
// 311.187 us; speedup vs baseline: 1.1657x; 1.1657x over previous
//
#include <hip/hip_runtime.h>
#include <math.h>

// SelfAttention fused pipeline, MI355X gfx950.
// B=4 S=2048 D=1024 H=8 DK=128.
// R5: flash v4 — 2x2 wave split (64 qrows x key-half per wave) halves LDS
// frag traffic vs flash2; BK=64 double-buffered K/V (one barrier/tile, DMA
// hidden under full body); all MFMA operands from LDS/regs (R4 lesson);
// V staged dk-pair-interleaved so vf reads are 2-way-bank free; l via VALU
// from bf16 P + LDS bounce; cross-wave O merge in epilogue. Packs fused.

typedef __bf16 bf16;
typedef __bf16 bf16x2 __attribute__((ext_vector_type(2)));
typedef __bf16 bf16x4 __attribute__((ext_vector_type(4)));
typedef __bf16 bf16x8 __attribute__((ext_vector_type(8)));
typedef float  f32x4  __attribute__((ext_vector_type(4)));
typedef float  f32x16 __attribute__((ext_vector_type(16)));
typedef int    i32x4  __attribute__((ext_vector_type(4)));

constexpr float QK_SCALE = 0.08838834764831845f;  // 1/sqrt(128)

__device__ __forceinline__ void load16_to_lds(const bf16* g, bf16* l) {
    __builtin_amdgcn_global_load_lds((const __attribute__((address_space(1))) void*)g,
                                     (__attribute__((address_space(3))) void*)l,
                                     16, 0, 0);
}

__device__ __forceinline__ int packbf2(float a, float b) {
    bf16x2 v; v[0] = (bf16)a; v[1] = (bf16)b;
    return __builtin_bit_cast(int, v);
}

// ---------------------------------------------------------------------------
// NT GEMM (validated R1-R3): C[m,n] = sum_k A[m,k]*B[n,k]. 128x128, BK=32.
// CMODE 1: QKV epilogue (Q,K->qk; V->vT transposed, MASKED; bias).
// CMODE 2: f32 C + bias (output projection).
// ---------------------------------------------------------------------------
template <int CMODE>
__global__ __launch_bounds__(256, 2)
void gemm_nt(const bf16* __restrict__ A, const bf16* __restrict__ Bm,
             void* __restrict__ Cv, bf16* __restrict__ vT,
             const float* __restrict__ bias, const int* __restrict__ gmask,
             int K, int lda, int ldb, int ldc)
{
    __shared__ alignas(16) bf16 As[128 * 32];
    __shared__ alignas(16) bf16 Bs[128 * 32];

    const int m0 = blockIdx.x * 128;
    const int n0 = blockIdx.y * 128;
    const int t    = threadIdx.x;
    const int lane = t & 63;
    const int wv   = t >> 6;
    const int mw   = (wv >> 1) * 64;
    const int nw   = (wv & 1) * 64;

    const int r1 = t >> 2;
    const int c1 = ((t & 3) - (r1 >> 1)) & 3;
    const int r2 = r1 + 64;
    const int c2 = ((t & 3) - (r2 >> 1)) & 3;

    const bf16* ga1 = A  + (long)(m0 + r1) * lda + c1 * 8;
    const bf16* ga2 = A  + (long)(m0 + r2) * lda + c2 * 8;
    const bf16* gb1 = Bm + (long)(n0 + r1) * ldb + c1 * 8;
    const bf16* gb2 = Bm + (long)(n0 + r2) * ldb + c2 * 8;
    bf16* la1 = &As[t * 8];
    bf16* la2 = &As[(256 + t) * 8];
    bf16* lb1 = &Bs[t * 8];
    bf16* lb2 = &Bs[(256 + t) * 8];

    const int fr = lane & 15;
    const int fq = lane >> 4;
    int aoff[4], boff[4];
#pragma unroll
    for (int i = 0; i < 4; ++i) {
        int Ra = mw + i * 16 + fr;
        aoff[i] = (Ra * 4 + ((fq + (Ra >> 1)) & 3)) * 8;
        int Rb = nw + i * 16 + fr;
        boff[i] = (Rb * 4 + ((fq + (Rb >> 1)) & 3)) * 8;
    }

    const f32x4 zero4 = {0.f, 0.f, 0.f, 0.f};
    f32x4 acc[4][4];
#pragma unroll
    for (int i = 0; i < 4; ++i)
#pragma unroll
        for (int j = 0; j < 4; ++j) acc[i][j] = zero4;

    for (int k0 = 0; k0 < K; k0 += 32) {
        __syncthreads();
        load16_to_lds(ga1, la1);
        load16_to_lds(ga2, la2);
        load16_to_lds(gb1, lb1);
        load16_to_lds(gb2, lb2);
        ga1 += 32; ga2 += 32; gb1 += 32; gb2 += 32;
        __syncthreads();
        bf16x8 af[4], bfr[4];
#pragma unroll
        for (int i = 0; i < 4; ++i) af[i]  = *(const bf16x8*)&As[aoff[i]];
#pragma unroll
        for (int j = 0; j < 4; ++j) bfr[j] = *(const bf16x8*)&Bs[boff[j]];
#pragma unroll
        for (int i = 0; i < 4; ++i)
#pragma unroll
            for (int j = 0; j < 4; ++j)
                acc[i][j] = __builtin_amdgcn_mfma_f32_16x16x32_bf16(af[i], bfr[j], acc[i][j], 0, 0, 0);
    }

    float bval = 0.f;
    if (CMODE == 1 || CMODE == 2) bval = bias[0];

#pragma unroll
    for (int i = 0; i < 4; ++i) {
        const int row0 = m0 + mw + i * 16 + fq * 4;
#pragma unroll
        for (int j = 0; j < 4; ++j) {
            const int col = n0 + nw + j * 16 + fr;
            if (CMODE == 2) {
                float* C = (float*)Cv;
#pragma unroll
                for (int r = 0; r < 4; ++r)
                    C[(long)(row0 + r) * ldc + col] = acc[i][j][r] + bval;
            } else {  // CMODE 1: QKV
                bf16* C = (bf16*)Cv;
                if (col < 2048) {
                    const float badd = (col < 1024) ? bval * QK_SCALE : bval;
#pragma unroll
                    for (int r = 0; r < 4; ++r)
                        C[(long)(row0 + r) * ldc + col] = (bf16)(acc[i][j][r] + badd);
                } else {  // V -> vT[(b*8+h)*128+dk][s], masked rows zeroed
                    const int vcol = col - 2048;
                    const int h  = vcol >> 7;
                    const int dk = vcol & 127;
                    const int b  = row0 >> 11;
                    const int s  = row0 & 2047;
                    i32x4 m4 = *(const i32x4*)(gmask + b * 2048 + s);
                    bf16x4 pack;
#pragma unroll
                    for (int r = 0; r < 4; ++r)
                        pack[r] = (bf16)((acc[i][j][r] + bval) * (float)m4[r]);
                    *(bf16x4*)&vT[((long)((b * 8 + h) * 128 + dk)) * 2048 + s] = pack;
                }
            }
        }
    }
}

// ---------------------------------------------------------------------------
// Flash v4. Block = 256 thr (4 waves) = 128 qrows x one (b,h).
// Wave (qg,kg): qrows qg*64+[0,64), keys kg*32+[0,32) of each 64-key tile.
// 32 key-tiles of 64, double-buffered K/V (4 x 16KB), ONE barrier/tile.
// K LDS tile: 64 key-rows x 16 chunks, swizzle pos=(c+row)&15.
// V LDS tile: 64 dkpair-rows x 16 chunks (dk-pair interleave), swizzle
//   pos=((dk&1)*8 + c + (dk>>1))&15 -> vf reads 2-way-free.
// S^T = K.Q^T (32x32x16), exp-only softmax, in-reg P transpose, l via VALU,
// O partial over kg merged through LDS at end.
// ---------------------------------------------------------------------------
__global__ __launch_bounds__(256, 2)
void flash4(const bf16* __restrict__ qk, const bf16* __restrict__ vT,
            const bf16* __restrict__ mbf, bf16* __restrict__ mh)
{
    __shared__ alignas(16) bf16 smem[4 * 64 * 128];   // KA KB VA VB, 16KB each
    __shared__ float lbuf[256];                        // [0:128) partial, [128:256) full
    bf16* KA = smem;
    bf16* KB = smem + 8192;
    bf16* VA = smem + 16384;
    bf16* VB = smem + 24576;

    const int qt = blockIdx.x, bh = blockIdx.y;
    const int b = bh >> 3, h = bh & 7;
    const int q0 = qt * 128;
    const int t = threadIdx.x, lane = t & 63, wv = t >> 6;
    const int qg = wv & 1, kg = wv >> 1;
    const int l31 = lane & 31, hl = lane >> 5;

    const bf16* Qb = qk + ((long)(b * 2048 + q0)) * 2048 + h * 128;
    const bf16* Kb = qk + (long)b * 2048 * 2048 + 1024 + h * 128;
    const bf16* Vb = vT + (long)bh * 128 * 2048;
    const bf16* mrow = mbf + b * 2048;

    // staging maps (slot s = rnd*256+t -> row=s>>4, pos=s&15)
    const int kr   = t >> 4;                  // row within round
    const int kc0  = ((t & 15) - kr) & 15;    // logical chunk for K-style tiles
    const int vpar = kc0 >> 3;                // V: dk parity
    const int vcol = (kc0 & 7) * 8;           // V: key-col offset
    bf16* ldKA = &KA[t * 8];
    bf16* ldKB = &KB[t * 8];
    bf16* ldVA = &VA[t * 8];
    bf16* ldVB = &VB[t * 8];

    // ---- stage Q (rows 0..63 -> KA, 64..127 -> KB), read Q B-frags ----
#pragma unroll
    for (int rnd = 0; rnd < 4; ++rnd)
        load16_to_lds(Qb + (long)(rnd * 16 + kr) * 2048 + kc0 * 8, ldKA + rnd * 2048);
#pragma unroll
    for (int rnd = 0; rnd < 4; ++rnd)
        load16_to_lds(Qb + (long)(64 + rnd * 16 + kr) * 2048 + kc0 * 8, ldKB + rnd * 2048);
    __syncthreads();
    bf16x8 qf[2][8];
    {
        const bf16* qsrc = qg ? KB : KA;
#pragma unroll
        for (int qnt = 0; qnt < 2; ++qnt)
#pragma unroll
            for (int kc = 0; kc < 8; ++kc) {
                int r64 = qnt * 32 + l31;
                int pos = ((kc * 2 + hl) + r64) & 15;
                qf[qnt][kc] = *(const bf16x8*)&qsrc[r64 * 128 + pos * 8];
            }
    }
    __syncthreads();

    // ---- prologue DMA: K(0)->KA, V(0)->VA ----
    {
        const bf16* ks = Kb + (long)kr * 2048 + kc0 * 8;
#pragma unroll
        for (int rnd = 0; rnd < 4; ++rnd)
            load16_to_lds(ks + (long)rnd * 16 * 2048, ldKA + rnd * 2048);
        const bf16* vs = Vb + (long)(2 * kr + vpar) * 2048 + vcol;
#pragma unroll
        for (int rnd = 0; rnd < 4; ++rnd)
            load16_to_lds(vs + (long)rnd * 32 * 2048, ldVA + rnd * 2048);
    }

    f32x16 O[2][4];
#pragma unroll
    for (int qnt = 0; qnt < 2; ++qnt)
#pragma unroll
        for (int dknt = 0; dknt < 4; ++dknt)
#pragma unroll
            for (int r = 0; r < 16; ++r) O[qnt][dknt][r] = 0.f;
    float l0 = 0.f, l1 = 0.f;

    const int krow = kg * 32 + l31;

    for (int tt = 0; tt < 32; ++tt) {
        const int t0 = tt * 64;
        __syncthreads();   // drains DMA(tt); fences reads of buf[tt&1] from tt-2

        // mask frags FIRST (oldest in vmcnt queue -> their wait leaves DMA in flight)
        bf16x8 mf0 = *(const bf16x8*)(mrow + t0 + kg * 32 + hl * 8);
        bf16x8 mf1 = *(const bf16x8*)(mrow + t0 + kg * 32 + 16 + hl * 8);

        // prefetch tile tt+1 into the other buffers (hidden under full body)
        if (tt < 31) {
            bf16* dK = (tt & 1) ? ldKA : ldKB;
            bf16* dV = (tt & 1) ? ldVA : ldVB;
            const bf16* ks = Kb + (long)(t0 + 64 + kr) * 2048 + kc0 * 8;
            const bf16* vs = Vb + (long)(2 * kr + vpar) * 2048 + (t0 + 64) + vcol;
#pragma unroll
            for (int rnd = 0; rnd < 4; ++rnd)
                load16_to_lds(ks + (long)rnd * 16 * 2048, dK + rnd * 2048);
#pragma unroll
            for (int rnd = 0; rnd < 4; ++rnd)
                load16_to_lds(vs + (long)rnd * 32 * 2048, dV + rnd * 2048);
        }
        const bf16* Kp = (tt & 1) ? KB : KA;
        const bf16* Vp = (tt & 1) ? VB : VA;

        // ---- S^T = K.Q^T for both qnt (shared kf reads) ----
        f32x16 S0, S1;
#pragma unroll
        for (int r = 0; r < 16; ++r) { S0[r] = 0.f; S1[r] = 0.f; }
#pragma unroll
        for (int kc = 0; kc < 8; ++kc) {
            int pos = ((kc * 2 + hl) + krow) & 15;
            bf16x8 kf = *(const bf16x8*)&Kp[krow * 128 + pos * 8];
            S0 = __builtin_amdgcn_mfma_f32_32x32x16_bf16(kf, qf[0][kc], S0, 0, 0, 0);
            S1 = __builtin_amdgcn_mfma_f32_32x32x16_bf16(kf, qf[1][kc], S1, 0, 0, 0);
        }

        // ---- exp + in-register transpose to P A-frags (per qnt) ----
        bf16x8 pf0[2], pf1[2];
        {
            int ownd[4][2], rcv[4][2];
#pragma unroll
            for (int g = 0; g < 4; ++g) {
                float e0 = __expf(S0[g * 4 + 0]);
                float e1 = __expf(S0[g * 4 + 1]);
                float e2 = __expf(S0[g * 4 + 2]);
                float e3 = __expf(S0[g * 4 + 3]);
                ownd[g][0] = packbf2(e0, e1);
                ownd[g][1] = packbf2(e2, e3);
            }
#pragma unroll
            for (int g = 0; g < 4; ++g) {
                rcv[g][0] = __shfl_xor(ownd[g][0], 32);
                rcv[g][1] = __shfl_xor(ownd[g][1], 32);
            }
#pragma unroll
            for (int kk = 0; kk < 2; ++kk) {
                i32x4 w;
                w[0] = hl ? rcv[2 * kk + 1][0] : ownd[2 * kk][0];
                w[1] = hl ? rcv[2 * kk + 1][1] : ownd[2 * kk][1];
                w[2] = hl ? ownd[2 * kk + 1][0] : rcv[2 * kk][0];
                w[3] = hl ? ownd[2 * kk + 1][1] : rcv[2 * kk][1];
                pf0[kk] = __builtin_bit_cast(bf16x8, w);
            }
        }
        {
            int ownd[4][2], rcv[4][2];
#pragma unroll
            for (int g = 0; g < 4; ++g) {
                float e0 = __expf(S1[g * 4 + 0]);
                float e1 = __expf(S1[g * 4 + 1]);
                float e2 = __expf(S1[g * 4 + 2]);
                float e3 = __expf(S1[g * 4 + 3]);
                ownd[g][0] = packbf2(e0, e1);
                ownd[g][1] = packbf2(e2, e3);
            }
#pragma unroll
            for (int g = 0; g < 4; ++g) {
                rcv[g][0] = __shfl_xor(ownd[g][0], 32);
                rcv[g][1] = __shfl_xor(ownd[g][1], 32);
            }
#pragma unroll
            for (int kk = 0; kk < 2; ++kk) {
                i32x4 w;
                w[0] = hl ? rcv[2 * kk + 1][0] : ownd[2 * kk][0];
                w[1] = hl ? rcv[2 * kk + 1][1] : ownd[2 * kk][1];
                w[2] = hl ? ownd[2 * kk + 1][0] : rcv[2 * kk][0];
                w[3] = hl ? ownd[2 * kk + 1][1] : rcv[2 * kk][1];
                pf1[kk] = __builtin_bit_cast(bf16x8, w);
            }
        }

        // ---- l += sum_j mask_j * P_j  (bf16 P, consistent with PV numerator) ----
#pragma unroll
        for (int j = 0; j < 8; ++j) {
            l0 += (float)pf0[0][j] * (float)mf0[j] + (float)pf0[1][j] * (float)mf1[j];
            l1 += (float)pf1[0][j] * (float)mf0[j] + (float)pf1[1][j] * (float)mf1[j];
        }

        // ---- O += P.V ----
#pragma unroll
        for (int dknt = 0; dknt < 4; ++dknt) {
            const int R2 = (dknt * 32 + l31) >> 1;
            const int par = l31 & 1;
#pragma unroll
            for (int kk = 0; kk < 2; ++kk) {
                int c = kg * 4 + kk * 2 + hl;
                int pos = (par * 8 + c + R2) & 15;
                bf16x8 vf = *(const bf16x8*)&Vp[R2 * 128 + pos * 8];
                O[0][dknt] = __builtin_amdgcn_mfma_f32_32x32x16_bf16(pf0[kk], vf, O[0][dknt], 0, 0, 0);
                O[1][dknt] = __builtin_amdgcn_mfma_f32_32x32x16_bf16(pf1[kk], vf, O[1][dknt], 0, 0, 0);
            }
        }
    }

    // ---- epilogue: merge kg partials, normalize, store with head reversal ----
    __syncthreads();
    float* mrg = (float*)smem;                 // 16384 floats
    float l0m = l0 + __shfl_xor(l0, 32);
    float l1m = l1 + __shfl_xor(l1, 32);

    if (kg == 1) {
        if (hl == 0) {
            lbuf[qg * 64 + l31] = l0m;
            lbuf[qg * 64 + 32 + l31] = l1m;
        }
        float* base = mrg + qg * 8192;
#pragma unroll
        for (int qnt = 0; qnt < 2; ++qnt)
#pragma unroll
            for (int dknt = 0; dknt < 4; ++dknt)
#pragma unroll
                for (int rb = 0; rb < 4; ++rb) {
                    f32x4 v;
#pragma unroll
                    for (int e = 0; e < 4; ++e) v[e] = O[qnt][dknt][rb * 4 + e];
                    *(f32x4*)&base[((((qnt * 4 + dknt) * 4 + rb) * 2 + hl) * 32 + l31) * 4] = v;
                }
    }
    __syncthreads();
    if (kg == 0) {
        float* base = mrg + qg * 8192;
#pragma unroll
        for (int qnt = 0; qnt < 2; ++qnt)
#pragma unroll
            for (int dknt = 0; dknt < 4; ++dknt)
#pragma unroll
                for (int rb = 0; rb < 4; ++rb) {
                    f32x4 v = *(const f32x4*)&base[((((qnt * 4 + dknt) * 4 + rb) * 2 + hl) * 32 + l31) * 4];
#pragma unroll
                    for (int e = 0; e < 4; ++e) O[qnt][dknt][rb * 4 + e] += v[e];
                }
        float lf0 = l0m + lbuf[qg * 64 + l31];
        float lf1 = l1m + lbuf[qg * 64 + 32 + l31];
        if (hl == 0) {
            lbuf[128 + qg * 64 + l31] = lf0;
            lbuf[128 + qg * 64 + 32 + l31] = lf1;
        }
    }
    __syncthreads();   // all waves participate
    if (kg == 0) {
        bf16* outb = mh + ((long)(b * 2048 + q0 + qg * 64)) * 1024 + (7 - h) * 128;
#pragma unroll
        for (int qnt = 0; qnt < 2; ++qnt)
#pragma unroll
            for (int r = 0; r < 16; ++r) {
                int row = (r & 3) + 8 * (r >> 2) + 4 * hl;
                float iv = 1.0f / lbuf[128 + qg * 64 + qnt * 32 + row];
#pragma unroll
                for (int dknt = 0; dknt < 4; ++dknt)
                    outb[(long)(qnt * 32 + row) * 1024 + dknt * 32 + l31] =
                        (bf16)(O[qnt][dknt][r] * iv);
            }
    }
}

// ---------------------------------------------------------------------------
// Fused packs: flat (x, Wo, mask -> bf16) + W_q/k/v transpose, one dispatch.
__global__ __launch_bounds__(256)
void pack_fused(const float* __restrict__ x, const float* __restrict__ Wo,
                const int* __restrict__ mask,
                const float* __restrict__ Wq, const float* __restrict__ Wk,
                const float* __restrict__ Wv,
                bf16* __restrict__ xb, bf16* __restrict__ wob,
                bf16* __restrict__ mbf, bf16* __restrict__ wt)
{
    __shared__ float tile[64][65];
    const long n1 = 8192L * 1024, n2 = 1024L * 1024;
    const int bx = blockIdx.x;
    if (bx < 9224) {
        long i = ((long)bx * 256 + threadIdx.x) * 4;
        if (i < n1) {
            float4 f = *(const float4*)(x + i);
            bf16x4 o;
            o[0] = (bf16)f.x; o[1] = (bf16)f.y; o[2] = (bf16)f.z; o[3] = (bf16)f.w;
            *(bf16x4*)(xb + i) = o;
        } else if (i < n1 + n2) {
            long j = i - n1;
            float4 f = *(const float4*)(Wo + j);
            bf16x4 o;
            o[0] = (bf16)f.x; o[1] = (bf16)f.y; o[2] = (bf16)f.z; o[3] = (bf16)f.w;
            *(bf16x4*)(wob + j) = o;
        } else {
            long j = i - n1 - n2;
            if (j < 8192) {
                i32x4 m = *(const i32x4*)(mask + j);
                bf16x4 o;
#pragma unroll
                for (int r = 0; r < 4; ++r) o[r] = (bf16)(float)m[r];
                *(bf16x4*)(mbf + j) = o;
            }
        }
        return;
    }
    // weight transpose part: id = ((which*8 + h)*32 + xx)
    const int id = bx - 9224;
    const int xx = id & 31;
    const int h  = (id >> 5) & 7;
    const int which = id >> 8;
    const float* W = (which == 0) ? Wq : (which == 1) ? Wk : Wv;
    const float scale = (which == 0) ? QK_SCALE : 1.0f;
    const int d0 = (xx >> 1) * 64;
    const int k0 = (xx & 1) * 64;
    const float* Wh = W + (long)h * 1024 * 128;
#pragma unroll
    for (int it = 0; it < 16; ++it) {
        int e = it * 256 + threadIdx.x;
        int r = e >> 6, c = e & 63;
        tile[r][c] = Wh[(long)(d0 + r) * 128 + (k0 + c)];
    }
    __syncthreads();
#pragma unroll
    for (int it = 0; it < 16; ++it) {
        int e = it * 256 + threadIdx.x;
        int rk = e >> 6, cd = e & 63;
        int n = which * 1024 + h * 128 + k0 + rk;
        wt[(long)n * 1024 + d0 + cd] = (bf16)(tile[cd][rk] * scale);
    }
}

// ---------------------------------------------------------------------------
extern "C" void kernel_launch(void* const* d_in, const int* in_sizes, int n_in,
                              void* d_out, int out_size, void* d_ws, size_t ws_size,
                              hipStream_t stream)
{
    const float* x    = (const float*)d_in[0];
    const int*   mask = (const int*)d_in[1];
    const float* Wq   = (const float*)d_in[2];
    const float* Wk   = (const float*)d_in[3];
    const float* Wv   = (const float*)d_in[4];
    const float* Wo   = (const float*)d_in[5];
    const float* bias = (const float*)d_in[6];
    float* out = (float*)d_out;

    char* w = (char*)d_ws;
    bf16* xb  = (bf16*)w; w += (size_t)8192 * 1024 * 2;        // 16 MB
    bf16* wt  = (bf16*)w; w += (size_t)3072 * 1024 * 2;        //  6 MB
    bf16* wob = (bf16*)w; w += (size_t)1024 * 1024 * 2;        //  2 MB
    bf16* qk  = (bf16*)w; w += (size_t)8192 * 2048 * 2;        // 32 MB
    bf16* vT  = (bf16*)w; w += (size_t)32 * 128 * 2048 * 2;    // 16 MB
    bf16* mh  = (bf16*)w; w += (size_t)8192 * 1024 * 2;        // 16 MB
    bf16* mbf = (bf16*)w; w += (size_t)4 * 2048 * 2;           // 16 KB

    pack_fused<<<9992, 256, 0, stream>>>(x, Wo, mask, Wq, Wk, Wv, xb, wob, mbf, wt);

    // QKV projection: M=8192 N=3072 K=1024 (V masked in epilogue)
    gemm_nt<1><<<dim3(64, 24), 256, 0, stream>>>(
        xb, wt, qk, vT, bias, mask, 1024, 1024, 1024, 2048);

    // fused attention
    flash4<<<dim3(16, 32), 256, 0, stream>>>(qk, vT, mbf, mh);

    // out = mh @ Wo^T + b: M=8192 N=1024 K=1024, fp32 out
    gemm_nt<2><<<dim3(64, 8), 256, 0, stream>>>(
        mh, wob, out, nullptr, bias, nullptr, 1024, 1024, 1024, 1024);
}